// Round 7
// baseline (1087.249 us; speedup 1.0000x reference)
//
#include <hip/hip_runtime.h>
#include <math.h>

#define NN 8192
#define DIN 256
#define DOUT 128
#define PST 20   // p_sh row stride (floats): 16B-aligned b128 reads, 8-way-max write conflicts

// ---- Kernel 1: h[i][d] = feat[i,:]·W[d,:] + b[d];  a1[i], a2[i]  (all f32) ----
// grid 8192 x 128. Layout-free VALU implementation.
__global__ __launch_bounds__(128) void k1_h(
    const float* __restrict__ feat, const float* __restrict__ W,
    const float* __restrict__ b, const float* __restrict__ w1,
    const float* __restrict__ b1, const float* __restrict__ w2,
    const float* __restrict__ b2,
    float* __restrict__ h, float* __restrict__ a1, float* __restrict__ a2,
    float* __restrict__ out_sentinel)
{
  __shared__ float frow[DIN];
  __shared__ float red[DOUT];
  const int i = blockIdx.x;
  const int d = threadIdx.x;              // 0..127
  if (i == 0 && d == 0) { out_sentinel[0] = 1.0f; out_sentinel[1] = 2.0f; }
  frow[d]       = feat[(size_t)i * DIN + d];
  frow[d + 128] = feat[(size_t)i * DIN + d + 128];
  __syncthreads();
  float s = 0.f;
  const float* wr = W + (size_t)d * DIN;
#pragma unroll 8
  for (int k = 0; k < DIN; ++k) s += frow[k] * wr[k];
  s += b[d];
  h[(size_t)i * DOUT + d] = s;

  red[d] = s * w1[d];
  __syncthreads();
  for (int t = 64; t > 0; t >>= 1) { if (d < t) red[d] += red[d + t]; __syncthreads(); }
  if (d == 0) a1[i] = red[0] + b1[0];
  __syncthreads();
  red[d] = s * w2[d];
  __syncthreads();
  for (int t = 64; t > 0; t >>= 1) { if (d < t) red[d] += red[d + t]; __syncthreads(); }
  if (d == 0) a2[i] = red[0] + b2[0];
}

// ---- Kernel 2: M[i] = leaky_relu(a1[i] + max_j a2[j])  (valid softmax shift) --
__global__ __launch_bounds__(256) void k2_m(const float* __restrict__ a1,
                                            const float* __restrict__ a2,
                                            float* __restrict__ M)
{
  __shared__ float red[256];
  const int t = threadIdx.x;
  float mx = -1e30f;
  for (int i = t; i < NN; i += 256) mx = fmaxf(mx, a2[i]);
  red[t] = mx;
  __syncthreads();
  for (int s = 128; s > 0; s >>= 1) {
    if (t < s) red[t] = fmaxf(red[t], red[t + s]);
    __syncthreads();
  }
  const float a2m = red[0];
  for (int i = t; i < NN; i += 256) {
    float y = a1[i] + a2m;
    M[i] = fmaxf(y, 0.01f * y);   // >= lrelu(a1[i]+a2[j]) for all j (monotone)
  }
}

// ---- Kernel 3: out[i][d] = (sum_j p_ij h[j][d]) / (sum_j p_ij) ---------------
// p_ij = adj ? exp(lrelu(a1_i+a2_j) - M_i) : 0  — fixed shift => additive partials.
// grid 512 x 256: block owns 16 rows. j processed in 128-chunks staged as p in LDS.
__global__ __launch_bounds__(256) void GATLayer_46024869544127_kernel(
    const int* __restrict__ adj, const float* __restrict__ h,
    const float* __restrict__ a1, const float* __restrict__ a2,
    const float* __restrict__ M, float* __restrict__ out)
{
  __shared__ float p_sh[128][PST];        // [jj][row], padded stride
  __shared__ float zAcc[16][4];
  const int tid = threadIdx.x;
  const int r0 = blockIdx.x * 16;
  const int grp = tid >> 7;               // 0..1 -> rows grp*8..grp*8+7
  const int d = tid & 127;
  float acc[8] = {0.f, 0.f, 0.f, 0.f, 0.f, 0.f, 0.f, 0.f};
  if (tid < 64) zAcc[tid >> 2][tid & 3] = 0.f;
  __syncthreads();

  for (int j0 = 0; j0 < NN; j0 += 128) {
    // phase A: p for 16 rows x 128 j  (adj reads coalesced along j)
#pragma unroll
    for (int pass = 0; pass < 8; ++pass) {
      const int row = pass * 2 + grp;
      const int jj = d;
      const int i = r0 + row;
      const int aj = adj[(size_t)i * NN + j0 + jj];
      const float y = a1[i] + a2[j0 + jj];
      const float ly = fmaxf(y, 0.01f * y);
      p_sh[jj][row] = (aj > 0) ? expf(ly - M[i]) : 0.f;
    }
    __syncthreads();

    // z partials: 64 threads, each sums 32 jj of its row
    if (tid < 64) {
      const int row = tid >> 2, qt = tid & 3;
      float zp = 0.f;
#pragma unroll
      for (int t = 0; t < 32; ++t) zp += p_sh[qt * 32 + t][row];
      zAcc[row][qt] += zp;
    }

    // accumulate: thread (grp,d) handles 8 rows for its d
    for (int jj = 0; jj < 128; ++jj) {
      const float hv = h[(size_t)(j0 + jj) * DOUT + d];
      const float* pr = &p_sh[jj][grp * 8];
#pragma unroll
      for (int r = 0; r < 8; ++r) acc[r] += pr[r] * hv;
    }
    __syncthreads();
  }

  // epilogue
#pragma unroll
  for (int r = 0; r < 8; ++r) {
    const int row = grp * 8 + r;
    const float zz = zAcc[row][0] + zAcc[row][1] + zAcc[row][2] + zAcc[row][3];
    out[(size_t)(r0 + row) * DOUT + d] = (zz > 0.f) ? (acc[r] / zz) : 0.f;
  }
}

extern "C" void kernel_launch(void* const* d_in, const int* in_sizes, int n_in,
                              void* d_out, int out_size, void* d_ws, size_t ws_size,
                              hipStream_t stream) {
  const float* feat = (const float*)d_in[0];
  const int* adj = (const int*)d_in[1];
  const float* W = (const float*)d_in[2];
  const float* b = (const float*)d_in[3];
  const float* w1 = (const float*)d_in[4];
  const float* b1 = (const float*)d_in[5];
  const float* w2 = (const float*)d_in[6];
  const float* b2 = (const float*)d_in[7];
  float* out = (float*)d_out;

  char* ws = (char*)d_ws;
  float* h  = (float*)ws;                         // 8192*128*4 = 4 MB
  float* a1 = h + (size_t)NN * DOUT;
  float* a2 = a1 + NN;
  float* M  = a2 + NN;

  k1_h<<<NN, 128, 0, stream>>>(feat, W, b, w1, b1, w2, b2, h, a1, a2, out);
  k2_m<<<1, 256, 0, stream>>>(a1, a2, M);
  GATLayer_46024869544127_kernel<<<NN / 16, 256, 0, stream>>>(adj, h, a1, a2, M, out);
}

// Round 8
// 974.265 us; speedup vs baseline: 1.1160x; 1.1160x over previous
//
#include <hip/hip_runtime.h>
#include <math.h>

#define NN 8192
#define DIN 256
#define DOUT 128
#define HS 8208   // padded hT row stride (bf16 elems)
#define PST 20    // p_sh row stride (floats)

typedef __attribute__((ext_vector_type(8))) short short8;
typedef __attribute__((ext_vector_type(8))) __bf16 bf16x8;
typedef __attribute__((ext_vector_type(4))) float f32x4;
typedef __attribute__((ext_vector_type(4))) unsigned short ushort4v;

__device__ __forceinline__ bf16x8 as_bf(short8 s) { return __builtin_bit_cast(bf16x8, s); }
__device__ __forceinline__ unsigned short f2bf(float f) {
  union { float ff; unsigned int i; } v; v.ff = f;
  unsigned int r = v.i + 0x7FFFu + ((v.i >> 16) & 1u);
  return (unsigned short)(r >> 16);
}

// ---- Kernel 1 (MFMA): h = feat @ W^T + b (f32 row-major + bf16 hT); a1, a2 ----
// grid 512 x block 64 (1 wave): 16 rows x 128 dims via 8 C-frags of 16x16x32.
// Layout assumptions under test:
//   A[m=lane&15][k=q*8+j] ; B[k=q*8+j][n=lane&15] ; D: col=lane&15, row=q*4+reg.
__global__ __launch_bounds__(64) void k1_h(
    const float* __restrict__ feat, const float* __restrict__ W,
    const float* __restrict__ bias, const float* __restrict__ w1,
    const float* __restrict__ b1, const float* __restrict__ w2,
    const float* __restrict__ b2,
    float* __restrict__ h, unsigned short* __restrict__ hT,
    float* __restrict__ a1, float* __restrict__ a2)
{
  const int lane = threadIdx.x;
  const int m = lane & 15, q = lane >> 4;
  const int r0 = blockIdx.x * 16;

  f32x4 acc[8] = {};
  const float* fRow = feat + (size_t)(r0 + m) * DIN + q * 8;
#pragma unroll
  for (int k0 = 0; k0 < DIN; k0 += 32) {
    short8 af;
#pragma unroll
    for (int t = 0; t < 8; ++t) af[t] = (short)f2bf(fRow[k0 + t]);
#pragma unroll
    for (int g = 0; g < 8; ++g) {
      const float* wRow = W + (size_t)(g * 16 + m) * DIN + k0 + q * 8;
      short8 wf;
#pragma unroll
      for (int t = 0; t < 8; ++t) wf[t] = (short)f2bf(wRow[t]);
      acc[g] = __builtin_amdgcn_mfma_f32_16x16x32_bf16(as_bf(af), as_bf(wf), acc[g], 0, 0, 0);
    }
  }
  float s1[4] = {0.f, 0.f, 0.f, 0.f}, s2[4] = {0.f, 0.f, 0.f, 0.f};
#pragma unroll
  for (int g = 0; g < 8; ++g) {
    const int d = g * 16 + m;
    const float bv = bias[d];
    const float w1v = w1[d];
    const float w2v = w2[d];
    ushort4v st;
#pragma unroll
    for (int r = 0; r < 4; ++r) {
      float v = acc[g][r] + bv;
      h[(size_t)(r0 + q * 4 + r) * DOUT + d] = v;   // row-major f32 for k3 (green)
      st[r] = f2bf(v);
      s1[r] += v * w1v;
      s2[r] += v * w2v;
    }
    *(ushort4v*)(hT + (size_t)d * HS + r0 + q * 4) = st;  // bf16 hT for future MFMA k3
  }
#pragma unroll
  for (int r = 0; r < 4; ++r) {
    s1[r] += __shfl_xor(s1[r], 1, 64); s2[r] += __shfl_xor(s2[r], 1, 64);
    s1[r] += __shfl_xor(s1[r], 2, 64); s2[r] += __shfl_xor(s2[r], 2, 64);
    s1[r] += __shfl_xor(s1[r], 4, 64); s2[r] += __shfl_xor(s2[r], 4, 64);
    s1[r] += __shfl_xor(s1[r], 8, 64); s2[r] += __shfl_xor(s2[r], 8, 64);
  }
  if (m == 0) {
    const float bb1 = b1[0], bb2 = b2[0];
#pragma unroll
    for (int r = 0; r < 4; ++r) {
      a1[r0 + q * 4 + r] = s1[r] + bb1;
      a2[r0 + q * 4 + r] = s2[r] + bb2;
    }
  }
}

// ---- Kernel 2: M[i] = leaky_relu(a1[i] + max_j a2[j])  (valid softmax shift) --
__global__ __launch_bounds__(256) void k2_m(const float* __restrict__ a1,
                                            const float* __restrict__ a2,
                                            float* __restrict__ M)
{
  __shared__ float red[256];
  const int t = threadIdx.x;
  float mx = -1e30f;
  for (int i = t; i < NN; i += 256) mx = fmaxf(mx, a2[i]);
  red[t] = mx;
  __syncthreads();
  for (int s = 128; s > 0; s >>= 1) {
    if (t < s) red[t] = fmaxf(red[t], red[t + s]);
    __syncthreads();
  }
  const float a2m = red[0];
  for (int i = t; i < NN; i += 256) {
    float y = a1[i] + a2m;
    M[i] = fmaxf(y, 0.01f * y);
  }
}

// ---- Kernel 3 (UNCHANGED green VALU version) ---------------------------------
__global__ __launch_bounds__(256) void GATLayer_46024869544127_kernel(
    const int* __restrict__ adj, const float* __restrict__ h,
    const float* __restrict__ a1, const float* __restrict__ a2,
    const float* __restrict__ M, float* __restrict__ out)
{
  __shared__ float p_sh[128][PST];
  __shared__ float zAcc[16][4];
  const int tid = threadIdx.x;
  const int r0 = blockIdx.x * 16;
  const int grp = tid >> 7;
  const int d = tid & 127;
  float acc[8] = {0.f, 0.f, 0.f, 0.f, 0.f, 0.f, 0.f, 0.f};
  if (tid < 64) zAcc[tid >> 2][tid & 3] = 0.f;
  __syncthreads();

  for (int j0 = 0; j0 < NN; j0 += 128) {
#pragma unroll
    for (int pass = 0; pass < 8; ++pass) {
      const int row = pass * 2 + grp;
      const int jj = d;
      const int i = r0 + row;
      const int aj = adj[(size_t)i * NN + j0 + jj];
      const float y = a1[i] + a2[j0 + jj];
      const float ly = fmaxf(y, 0.01f * y);
      p_sh[jj][row] = (aj > 0) ? expf(ly - M[i]) : 0.f;
    }
    __syncthreads();

    if (tid < 64) {
      const int row = tid >> 2, qt = tid & 3;
      float zp = 0.f;
#pragma unroll
      for (int t = 0; t < 32; ++t) zp += p_sh[qt * 32 + t][row];
      zAcc[row][qt] += zp;
    }

    for (int jj = 0; jj < 128; ++jj) {
      const float hv = h[(size_t)(j0 + jj) * DOUT + d];
      const float* pr = &p_sh[jj][grp * 8];
#pragma unroll
      for (int r = 0; r < 8; ++r) acc[r] += pr[r] * hv;
    }
    __syncthreads();
  }

#pragma unroll
  for (int r = 0; r < 8; ++r) {
    const int row = grp * 8 + r;
    const float zz = zAcc[row][0] + zAcc[row][1] + zAcc[row][2] + zAcc[row][3];
    out[(size_t)(r0 + row) * DOUT + d] = (zz > 0.f) ? (acc[r] / zz) : 0.f;
  }
}

extern "C" void kernel_launch(void* const* d_in, const int* in_sizes, int n_in,
                              void* d_out, int out_size, void* d_ws, size_t ws_size,
                              hipStream_t stream) {
  const float* feat = (const float*)d_in[0];
  const int* adj = (const int*)d_in[1];
  const float* W = (const float*)d_in[2];
  const float* b = (const float*)d_in[3];
  const float* w1 = (const float*)d_in[4];
  const float* b1 = (const float*)d_in[5];
  const float* w2 = (const float*)d_in[6];
  const float* b2 = (const float*)d_in[7];
  float* out = (float*)d_out;

  char* ws = (char*)d_ws;
  float* h = (float*)ws;                                    // 4 MB f32 row-major
  unsigned short* hT = (unsigned short*)(ws + (size_t)NN * DOUT * 4);  // ~2.1 MB bf16
  float* a1 = (float*)(ws + (size_t)NN * DOUT * 4 + (size_t)DOUT * HS * 2);
  float* a2 = a1 + NN;
  float* M  = a2 + NN;

  k1_h<<<512, 64, 0, stream>>>(feat, W, b, w1, b1, w2, b2, h, hT, a1, a2);
  k2_m<<<1, 256, 0, stream>>>(a1, a2, M);
  GATLayer_46024869544127_kernel<<<NN / 16, 256, 0, stream>>>(adj, h, a1, a2, M, out);
}